// Round 14
// baseline (177.078 us; speedup 1.0000x reference)
//
#include <hip/hip_runtime.h>
#include <hip/hip_bf16.h>

// dist[n][m] = |x_n|^2 + |y_m|^2 - 2 x_n.y_m
// N=M=8192, D=128, f32 in/out. HBM-write-bound (256 MiB out).
//
// prep_kernel: x,y f32 -> bf16 ONCE into d_ws, packed in MFMA-fragment order.
// dist_main:   32x1024 tile at OCC 3 (the config R13 missed): 4 KiB NT row
//   runs, B:out = 2:1 (R7's ratio). Register diet: LDS holds -2*cross only;
//   +xn+yn fused in readback (kills ynv[16]); b streamed (live b = 1).
//   LDS diet: 4-pass epilogue, 8 rows x 4 KiB = 32 KiB.
//   Ladder: 64B=3.0, 512B=4.4, 2KiB=5.0 TB/s (occ3); 4KiB@occ3 = this test.

typedef __attribute__((ext_vector_type(8))) short short8;
typedef __attribute__((ext_vector_type(4))) float f32x4;

#define NROW 8192
#define DIM  128

__device__ __forceinline__ short f2bf(float f) {
    unsigned u = __builtin_bit_cast(unsigned, f);
    unsigned r = u + 0x7FFFu + ((u >> 16) & 1u);
    return (short)(r >> 16);
}

// LDS-only barrier: waits LDS ops, leaves global NT stores (vmcnt) in flight.
__device__ __forceinline__ void barrier_lgkm() {
    asm volatile("s_waitcnt lgkmcnt(0)" ::: "memory");
    __builtin_amdgcn_s_barrier();
    __builtin_amdgcn_sched_barrier(0);
}

// ---------------- prep: pack bf16 fragments + row norms ----------------
// chunk(g,kk,lg,lr) = bf16 of M[g*16+lr][kk*32+lg*8 .. +8]
// => main-kernel frag load: 64 lanes read ((g*4+kk)*64+lane)*16B, contiguous.
__global__ __launch_bounds__(256)
void prep_kernel(const float* __restrict__ X, const float* __restrict__ Y,
                 unsigned short* __restrict__ Xp, unsigned short* __restrict__ Yp,
                 float* __restrict__ xn, float* __restrict__ yn)
{
    const int t   = blockIdx.x * 256 + threadIdx.x;   // 0 .. 262143
    const int sel = t >> 17;                          // 0 = x, 1 = y
    const int c   = t & 131071;
    const int row = c >> 4;
    const int sub = c & 15;

    const float* src = (sel ? Y : X) + (size_t)row * DIM + sub * 8;
    f32x4 v0 = ((const f32x4*)src)[0];
    f32x4 v1 = ((const f32x4*)src)[1];

    short8 p;
    p[0]=f2bf(v0[0]); p[1]=f2bf(v0[1]); p[2]=f2bf(v0[2]); p[3]=f2bf(v0[3]);
    p[4]=f2bf(v1[0]); p[5]=f2bf(v1[1]); p[6]=f2bf(v1[2]); p[7]=f2bf(v1[3]);

    float part = v0[0]*v0[0] + v0[1]*v0[1] + v0[2]*v0[2] + v0[3]*v0[3]
               + v1[0]*v1[0] + v1[1]*v1[1] + v1[2]*v1[2] + v1[3]*v1[3];
    part += __shfl_xor(part, 1, 16);
    part += __shfl_xor(part, 2, 16);
    part += __shfl_xor(part, 4, 16);
    part += __shfl_xor(part, 8, 16);

    const int g = row >> 4, lr = row & 15, kk = sub >> 2, lg = sub & 3;
    unsigned short* dst = (sel ? Yp : Xp) + (size_t)(((g*4 + kk)*64) + lg*16 + lr) * 8;
    *(short8*)dst = p;
    if (sub == 0) (sel ? yn : xn)[row] = part;
}

// ---------------- main: 32x1024 tile, 4 waves x (32 x 256), occ 3 ----------------
__global__ __launch_bounds__(256, 3)
void dist_main(const unsigned short* __restrict__ Xp,
               const unsigned short* __restrict__ Yp,
               const float* __restrict__ xn, const float* __restrict__ yn,
               float* __restrict__ out)
{
    // 32 KiB: 8 rows x 4 KiB; 16B slots XOR-swizzled by row (rl<8).
    __shared__ char lds[8 * 4096];

    const int bid = blockIdx.x;                     // 0..2047
    const int wg  = (bid & 7) * 256 + (bid >> 3);   // XCD-bijective (2048%8==0)
    const int R0  = (wg >> 3) * 32;                 // 256 row bands
    const int C0  = (wg & 7) * 1024;                // 8 col tiles

    const int t    = threadIdx.x;
    const int w    = t >> 6, lane = t & 63;
    const int lr   = lane & 15, lg = lane >> 4;

    const short8* Ap = (const short8*)Xp;
    const short8* Bp = (const short8*)Yp;
    const int ga = R0 >> 4;                         // 2 row groups: ga, ga+1
    const int gb = (C0 >> 4) + w * 16;              // 16 col groups per wave

    f32x4 acc[2][16];
    #pragma unroll
    for (int j = 0; j < 2; ++j)
        #pragma unroll
        for (int i = 0; i < 16; ++i)
            acc[j][i] = (f32x4){0.f, 0.f, 0.f, 0.f};

    #pragma unroll
    for (int kk = 0; kk < 4; ++kk) {
        short8 a0 = Ap[(size_t)(ga * 4 + kk) * 64 + lane];
        short8 a1 = Ap[(size_t)((ga + 1) * 4 + kk) * 64 + lane];
        // stream b one-at-a-time: live b = 1 frag (compiler may pipeline)
        #pragma unroll
        for (int i = 0; i < 16; ++i) {
            short8 b = Bp[(size_t)((gb + i) * 4 + kk) * 64 + lane];
            // D = mfma(B, A): D-row = y-index (out col), D-col = x-index (out row)
            acc[0][i] = __builtin_amdgcn_mfma_f32_16x16x32_bf16(b, a0, acc[0][i], 0, 0, 0);
            acc[1][i] = __builtin_amdgcn_mfma_f32_16x16x32_bf16(b, a1, acc[1][i], 0, 0, 0);
        }
    }

    // acc[j][i][r]:  n = R0 + j*16 + lr                (out row)
    //                m = C0 + w*256 + i*16 + lg*4 + r  (out col, f32x4-contig)
    // Four-pass epilogue (8 rows each): deposit -2*acc into swizzled LDS;
    // readback adds xn[row] (row-uniform) + yn 16B vector (L1-hot) and emits
    // 4x back-to-back 1 KiB NT stores per row = 4 KiB sequential.
    #pragma unroll
    for (int p = 0; p < 4; ++p) {
        const int jp = p >> 1, half = p & 1;
        if ((lr >> 3) == half) {
            const int rl = lr & 7;                   // local row 0..7
            #pragma unroll
            for (int i = 0; i < 16; ++i) {
                f32x4 o;
                #pragma unroll
                for (int r = 0; r < 4; ++r)
                    o[r] = -2.0f * acc[jp][i][r];
                const int slotb = w * 1024 + i * 64 + lg * 16;
                *(f32x4*)(lds + rl * 4096 + (slotb ^ (rl << 4))) = o;
            }
        }
        barrier_lgkm();
        #pragma unroll
        for (int rr = 0; rr < 2; ++rr) {
            const int lrow = w * 2 + rr;             // 0..7
            const int grow = R0 + p * 8 + lrow;
            const float xrow = xn[grow];
            const size_t gbase = (size_t)grow * NROW + C0;
            #pragma unroll
            for (int h = 0; h < 4; ++h) {
                const int chunk = h * 64 + lane;     // logical 16B chunk in row
                f32x4 v = *(const f32x4*)(lds + lrow * 4096 + ((chunk * 16) ^ (lrow << 4)));
                f32x4 yv = *(const f32x4*)(yn + C0 + chunk * 4);
                f32x4 o;
                #pragma unroll
                for (int r = 0; r < 4; ++r)
                    o[r] = v[r] + xrow + yv[r];
                __builtin_nontemporal_store(o, (f32x4*)(out + gbase + chunk * 4));
            }
        }
        if (p < 3) barrier_lgkm();
    }
}

// ---------------- fallback if ws_size too small ----------------
__global__ __launch_bounds__(256, 2)
void dist_fallback(const float* __restrict__ X, const float* __restrict__ Y,
                   float* __restrict__ out)
{
    __shared__ unsigned short As[128 * DIM];
    __shared__ unsigned short Bs[128 * DIM];
    __shared__ float xs[128];
    __shared__ float ys[128];

    const int t = threadIdx.x, bid = blockIdx.x;
    const int R0 = (bid >> 6) * 128, C0 = (bid & 63) * 128;
    {
        const float* gx = X + (size_t)R0 * DIM;
        const float* gy = Y + (size_t)C0 * DIM;
        char* lx = (char*)As; char* ly = (char*)Bs;
        #pragma unroll
        for (int i = 0; i < 8; ++i) {
            int q = i * 256 + t, r = q >> 4, c = q & 15;
            f32x4 a0 = ((const f32x4*)(gx + q*8))[0], a1 = ((const f32x4*)(gx + q*8))[1];
            f32x4 b0 = ((const f32x4*)(gy + q*8))[0], b1 = ((const f32x4*)(gy + q*8))[1];
            short8 pa, pb;
            #pragma unroll
            for (int e = 0; e < 4; ++e) { pa[e]=f2bf(a0[e]); pa[e+4]=f2bf(a1[e]); pb[e]=f2bf(b0[e]); pb[e+4]=f2bf(b1[e]); }
            int off = r * 256 + ((c * 16) ^ ((r & 7) << 4));
            *(short8*)(lx + off) = pa; *(short8*)(ly + off) = pb;
        }
    }
    {
        const float* row = (t < 128) ? (X + (size_t)(R0 + t) * DIM) : (Y + (size_t)(C0 + t - 128) * DIM);
        float s = 0.f;
        #pragma unroll
        for (int i = 0; i < DIM; i += 4) { f32x4 v = *(const f32x4*)(row + i); s += v[0]*v[0]+v[1]*v[1]+v[2]*v[2]+v[3]*v[3]; }
        if (t < 128) xs[t] = s; else ys[t - 128] = s;
    }
    __syncthreads();
    const int wid = t >> 6, lane = t & 63, wr = wid >> 1, wc = wid & 1, lg = lane >> 4, lrr = lane & 15;
    f32x4 acc[4][4];
    #pragma unroll
    for (int i = 0; i < 4; ++i) for (int j = 0; j < 4; ++j) acc[i][j] = (f32x4){0,0,0,0};
    const char* lA = (const char*)As; const char* lB = (const char*)Bs;
    #pragma unroll
    for (int kk = 0; kk < 4; ++kk) {
        const int kb = kk * 64 + lg * 16;
        short8 a[4], b[4];
        #pragma unroll
        for (int i = 0; i < 4; ++i) {
            int ar = wr*64 + i*16 + lrr; a[i] = *(const short8*)(lA + ar*256 + (kb ^ ((ar&7)<<4)));
            int br = wc*64 + i*16 + lrr; b[i] = *(const short8*)(lB + br*256 + (kb ^ ((br&7)<<4)));
        }
        #pragma unroll
        for (int i = 0; i < 4; ++i) for (int j = 0; j < 4; ++j)
            acc[i][j] = __builtin_amdgcn_mfma_f32_16x16x32_bf16(a[i], b[j], acc[i][j], 0, 0, 0);
    }
    #pragma unroll
    for (int i = 0; i < 4; ++i) for (int j = 0; j < 4; ++j) {
        const int row_l = wr*64 + i*16 + lg*4, col_l = wc*64 + j*16 + lrr;
        const float yv = ys[col_l];
        float* po = out + (size_t)(R0 + row_l) * NROW + (C0 + col_l);
        #pragma unroll
        for (int r = 0; r < 4; ++r) po[(size_t)r * NROW] = xs[row_l + r] + yv - 2.0f * acc[i][j][r];
    }
}

extern "C" void kernel_launch(void* const* d_in, const int* in_sizes, int n_in,
                              void* d_out, int out_size, void* d_ws, size_t ws_size,
                              hipStream_t stream) {
    const float* x = (const float*)d_in[0];
    const float* y = (const float*)d_in[1];
    float* out = (float*)d_out;

    const size_t XP_OFF = 0;
    const size_t YP_OFF = 2097152;            // 8192*128*2
    const size_t XN_OFF = 4194304;
    const size_t YN_OFF = 4194304 + 32768;
    const size_t NEED   = 4194304 + 65536;

    if (ws_size >= NEED) {
        char* w = (char*)d_ws;
        unsigned short* Xp = (unsigned short*)(w + XP_OFF);
        unsigned short* Yp = (unsigned short*)(w + YP_OFF);
        float* xnp = (float*)(w + XN_OFF);
        float* ynp = (float*)(w + YN_OFF);
        prep_kernel<<<1024, 256, 0, stream>>>(x, y, Xp, Yp, xnp, ynp);
        dist_main<<<2048, 256, 0, stream>>>(Xp, Yp, xnp, ynp, out);
    } else {
        dist_fallback<<<4096, 256, 0, stream>>>(x, y, out);
    }
}

// Round 15
// 70.241 us; speedup vs baseline: 2.5210x; 2.5210x over previous
//
#include <hip/hip_runtime.h>
#include <hip/hip_bf16.h>

// dist[n][m] = |x_n|^2 + |y_m|^2 - 2 x_n.y_m
// N=M=8192, D=128, f32 in/out. HBM-write-bound (256 MiB out).
//
// prep_kernel: x,y f32 -> bf16 ONCE into d_ws, packed in MFMA-fragment order.
// dist_main:   R7 geometry (32x512 tile, 2 KiB NT runs, grid 4096) at OCC 4:
//   b-frags streamed singly (live b = 8 VGPR) to fit the (256,4) 128-VGPR cap.
//   acc 64 + a 16 + b 8 + misc ~ 120 < 128. LDS 32 KiB <= 40 KiB/blk @ occ4.
//   Theory: stores are ~70% of block time; 16 waves/CU (vs 12) raises the
//   NT-store issue duty cycle toward the 6.9 TB/s memset ceiling.

typedef __attribute__((ext_vector_type(8))) short short8;
typedef __attribute__((ext_vector_type(4))) float f32x4;

#define NROW 8192
#define DIM  128

__device__ __forceinline__ short f2bf(float f) {
    unsigned u = __builtin_bit_cast(unsigned, f);
    unsigned r = u + 0x7FFFu + ((u >> 16) & 1u);
    return (short)(r >> 16);
}

// LDS-only barrier: waits LDS ops, leaves global NT stores (vmcnt) in flight.
__device__ __forceinline__ void barrier_lgkm() {
    asm volatile("s_waitcnt lgkmcnt(0)" ::: "memory");
    __builtin_amdgcn_s_barrier();
    __builtin_amdgcn_sched_barrier(0);
}

// ---------------- prep: pack bf16 fragments + row norms ----------------
// chunk(g,kk,lg,lr) = bf16 of M[g*16+lr][kk*32+lg*8 .. +8]
// => main-kernel frag load: 64 lanes read ((g*4+kk)*64+lane)*16B, contiguous.
__global__ __launch_bounds__(256)
void prep_kernel(const float* __restrict__ X, const float* __restrict__ Y,
                 unsigned short* __restrict__ Xp, unsigned short* __restrict__ Yp,
                 float* __restrict__ xn, float* __restrict__ yn)
{
    const int t   = blockIdx.x * 256 + threadIdx.x;   // 0 .. 262143
    const int sel = t >> 17;                          // 0 = x, 1 = y
    const int c   = t & 131071;
    const int row = c >> 4;
    const int sub = c & 15;

    const float* src = (sel ? Y : X) + (size_t)row * DIM + sub * 8;
    f32x4 v0 = ((const f32x4*)src)[0];
    f32x4 v1 = ((const f32x4*)src)[1];

    short8 p;
    p[0]=f2bf(v0[0]); p[1]=f2bf(v0[1]); p[2]=f2bf(v0[2]); p[3]=f2bf(v0[3]);
    p[4]=f2bf(v1[0]); p[5]=f2bf(v1[1]); p[6]=f2bf(v1[2]); p[7]=f2bf(v1[3]);

    float part = v0[0]*v0[0] + v0[1]*v0[1] + v0[2]*v0[2] + v0[3]*v0[3]
               + v1[0]*v1[0] + v1[1]*v1[1] + v1[2]*v1[2] + v1[3]*v1[3];
    part += __shfl_xor(part, 1, 16);
    part += __shfl_xor(part, 2, 16);
    part += __shfl_xor(part, 4, 16);
    part += __shfl_xor(part, 8, 16);

    const int g = row >> 4, lr = row & 15, kk = sub >> 2, lg = sub & 3;
    unsigned short* dst = (sel ? Yp : Xp) + (size_t)(((g*4 + kk)*64) + lg*16 + lr) * 8;
    *(short8*)dst = p;
    if (sub == 0) (sel ? yn : xn)[row] = part;
}

// ---------------- main: 32x512 tile, 4 waves x (32 x 128) strips, occ 4 ----------------
__global__ __launch_bounds__(256, 4)
void dist_main(const unsigned short* __restrict__ Xp,
               const unsigned short* __restrict__ Yp,
               const float* __restrict__ xn, const float* __restrict__ yn,
               float* __restrict__ out)
{
    // 32 KiB: 16 rows x 2 KiB; 16B slots XOR-swizzled by (row&7).
    __shared__ char lds[16 * 2048];

    const int bid = blockIdx.x;
    const int wg  = (bid & 7) * 512 + (bid >> 3);   // XCD-bijective swizzle
    const int R0  = (wg >> 4) * 32;                 // 256 row bands
    const int C0  = (wg & 15) * 512;                // 16 col tiles

    const int t    = threadIdx.x;
    const int w    = t >> 6, lane = t & 63;
    const int lr   = lane & 15, lg = lane >> 4;

    const short8* Ap = (const short8*)Xp;
    const short8* Bp = (const short8*)Yp;
    const int ga = R0 >> 4;                         // 2 row groups: ga, ga+1
    const int gb = (C0 >> 4) + w * 8;               // 8 col groups per wave

    f32x4 acc[2][8];
    #pragma unroll
    for (int j = 0; j < 2; ++j)
        #pragma unroll
        for (int i = 0; i < 8; ++i)
            acc[j][i] = (f32x4){0.f, 0.f, 0.f, 0.f};

    #pragma unroll
    for (int kk = 0; kk < 4; ++kk) {
        short8 a0 = Ap[(size_t)(ga * 4 + kk) * 64 + lane];
        short8 a1 = Ap[(size_t)((ga + 1) * 4 + kk) * 64 + lane];
        // stream b singly: live b = 8 VGPR, fits the (256,4) 128-VGPR cap
        #pragma unroll
        for (int i = 0; i < 8; ++i) {
            short8 b = Bp[(size_t)((gb + i) * 4 + kk) * 64 + lane];
            // D = mfma(B, A): D-row = y-index (out col), D-col = x-index (out row)
            acc[0][i] = __builtin_amdgcn_mfma_f32_16x16x32_bf16(b, a0, acc[0][i], 0, 0, 0);
            acc[1][i] = __builtin_amdgcn_mfma_f32_16x16x32_bf16(b, a1, acc[1][i], 0, 0, 0);
        }
    }

    // acc[j][i][r]:  n = R0 + j*16 + lr                (out row)
    //                m = C0 + w*128 + i*16 + lg*4 + r  (out col, f32x4-contig)
    float xnv[2];
    xnv[0] = xn[R0 + lr];
    xnv[1] = xn[R0 + 16 + lr];

    // Two-pass epilogue (16 rows each): deposit fused values into swizzled
    // LDS (yn read 16B/lane from L1 here, not cached in regs -- VGPR diet),
    // then each wave streams 4 rows as 2x 1KiB-contiguous NT stores per row.
    #pragma unroll
    for (int p = 0; p < 2; ++p) {
        #pragma unroll
        for (int i = 0; i < 8; ++i) {
            f32x4 yv = *(const f32x4*)(yn + C0 + w * 128 + i * 16 + lg * 4);
            f32x4 o;
            #pragma unroll
            for (int r = 0; r < 4; ++r)
                o[r] = xnv[p] + yv[r] - 2.0f * acc[p][i][r];
            const int slotb = w * 512 + i * 64 + lg * 16;
            *(f32x4*)(lds + lr * 2048 + (slotb ^ ((lr & 7) << 4))) = o;
        }
        barrier_lgkm();
        #pragma unroll
        for (int rr = 0; rr < 4; ++rr) {
            const int lrow = w * 4 + rr;
            const size_t gbase = (size_t)(R0 + p * 16 + lrow) * NROW + C0;
            #pragma unroll
            for (int h = 0; h < 2; ++h) {
                const int s16 = h * 64 + lane;       // logical 16B chunk in row
                f32x4 v = *(const f32x4*)(lds + lrow * 2048 + ((s16 * 16) ^ ((lrow & 7) << 4)));
                __builtin_nontemporal_store(v, (f32x4*)(out + gbase + s16 * 4));
            }
        }
        if (p == 0) barrier_lgkm();
    }
}

// ---------------- fallback if ws_size too small ----------------
__global__ __launch_bounds__(256, 2)
void dist_fallback(const float* __restrict__ X, const float* __restrict__ Y,
                   float* __restrict__ out)
{
    __shared__ unsigned short As[128 * DIM];
    __shared__ unsigned short Bs[128 * DIM];
    __shared__ float xs[128];
    __shared__ float ys[128];

    const int t = threadIdx.x, bid = blockIdx.x;
    const int R0 = (bid >> 6) * 128, C0 = (bid & 63) * 128;
    {
        const float* gx = X + (size_t)R0 * DIM;
        const float* gy = Y + (size_t)C0 * DIM;
        char* lx = (char*)As; char* ly = (char*)Bs;
        #pragma unroll
        for (int i = 0; i < 8; ++i) {
            int q = i * 256 + t, r = q >> 4, c = q & 15;
            f32x4 a0 = ((const f32x4*)(gx + q*8))[0], a1 = ((const f32x4*)(gx + q*8))[1];
            f32x4 b0 = ((const f32x4*)(gy + q*8))[0], b1 = ((const f32x4*)(gy + q*8))[1];
            short8 pa, pb;
            #pragma unroll
            for (int e = 0; e < 4; ++e) { pa[e]=f2bf(a0[e]); pa[e+4]=f2bf(a1[e]); pb[e]=f2bf(b0[e]); pb[e+4]=f2bf(b1[e]); }
            int off = r * 256 + ((c * 16) ^ ((r & 7) << 4));
            *(short8*)(lx + off) = pa; *(short8*)(ly + off) = pb;
        }
    }
    {
        const float* row = (t < 128) ? (X + (size_t)(R0 + t) * DIM) : (Y + (size_t)(C0 + t - 128) * DIM);
        float s = 0.f;
        #pragma unroll
        for (int i = 0; i < DIM; i += 4) { f32x4 v = *(const f32x4*)(row + i); s += v[0]*v[0]+v[1]*v[1]+v[2]*v[2]+v[3]*v[3]; }
        if (t < 128) xs[t] = s; else ys[t - 128] = s;
    }
    __syncthreads();
    const int wid = t >> 6, lane = t & 63, wr = wid >> 1, wc = wid & 1, lg = lane >> 4, lrr = lane & 15;
    f32x4 acc[4][4];
    #pragma unroll
    for (int i = 0; i < 4; ++i) for (int j = 0; j < 4; ++j) acc[i][j] = (f32x4){0,0,0,0};
    const char* lA = (const char*)As; const char* lB = (const char*)Bs;
    #pragma unroll
    for (int kk = 0; kk < 4; ++kk) {
        const int kb = kk * 64 + lg * 16;
        short8 a[4], b[4];
        #pragma unroll
        for (int i = 0; i < 4; ++i) {
            int ar = wr*64 + i*16 + lrr; a[i] = *(const short8*)(lA + ar*256 + (kb ^ ((ar&7)<<4)));
            int br = wc*64 + i*16 + lrr; b[i] = *(const short8*)(lB + br*256 + (kb ^ ((br&7)<<4)));
        }
        #pragma unroll
        for (int i = 0; i < 4; ++i) for (int j = 0; j < 4; ++j)
            acc[i][j] = __builtin_amdgcn_mfma_f32_16x16x32_bf16(a[i], b[j], acc[i][j], 0, 0, 0);
    }
    #pragma unroll
    for (int i = 0; i < 4; ++i) for (int j = 0; j < 4; ++j) {
        const int row_l = wr*64 + i*16 + lg*4, col_l = wc*64 + j*16 + lrr;
        const float yv = ys[col_l];
        float* po = out + (size_t)(R0 + row_l) * NROW + (C0 + col_l);
        #pragma unroll
        for (int r = 0; r < 4; ++r) po[(size_t)r * NROW] = xs[row_l + r] + yv - 2.0f * acc[i][j][r];
    }
}

extern "C" void kernel_launch(void* const* d_in, const int* in_sizes, int n_in,
                              void* d_out, int out_size, void* d_ws, size_t ws_size,
                              hipStream_t stream) {
    const float* x = (const float*)d_in[0];
    const float* y = (const float*)d_in[1];
    float* out = (float*)d_out;

    const size_t XP_OFF = 0;
    const size_t YP_OFF = 2097152;            // 8192*128*2
    const size_t XN_OFF = 4194304;
    const size_t YN_OFF = 4194304 + 32768;
    const size_t NEED   = 4194304 + 65536;

    if (ws_size >= NEED) {
        char* w = (char*)d_ws;
        unsigned short* Xp = (unsigned short*)(w + XP_OFF);
        unsigned short* Yp = (unsigned short*)(w + YP_OFF);
        float* xnp = (float*)(w + XN_OFF);
        float* ynp = (float*)(w + YN_OFF);
        prep_kernel<<<1024, 256, 0, stream>>>(x, y, Xp, Yp, xnp, ynp);
        dist_main<<<4096, 256, 0, stream>>>(Xp, Yp, xnp, ynp, out);
    } else {
        dist_fallback<<<4096, 256, 0, stream>>>(x, y, out);
    }
}

// Round 16
// 58.969 us; speedup vs baseline: 3.0029x; 1.1912x over previous
//
#include <hip/hip_runtime.h>
#include <hip/hip_bf16.h>

// dist[n][m] = |x_n|^2 + |y_m|^2 - 2 x_n.y_m
// N=M=8192, D=128, f32 in/out. HBM-write-bound (256 MiB out, floor ~42us).
//
// FINAL (= R7, best of 15 rounds: 59.1us, ~5.0 TB/s effective write BW):
// prep_kernel: x,y f32 -> bf16 ONCE into d_ws, packed in MFMA-fragment order.
// dist_main:   32x512 tile/block, occ 3, 4 waves x (32x128) strips;
//   fused epilogue through swizzled LDS -> 2 KiB/row NT store runs;
//   lgkm-only barriers keep NT stores fire-and-forget.
// Axis ledger: run-length 64B/512B/2KiB = 3.0/4.4/5.0 TB/s (wins);
//   4KiB runs infeasible at occ3 (VGPR/LDS geometry); occ2/occ4 lose;
//   plain stores lose; drain-free barriers null; persistent overlap loses.

typedef __attribute__((ext_vector_type(8))) short short8;
typedef __attribute__((ext_vector_type(4))) float f32x4;

#define NROW 8192
#define DIM  128

__device__ __forceinline__ short f2bf(float f) {
    unsigned u = __builtin_bit_cast(unsigned, f);
    unsigned r = u + 0x7FFFu + ((u >> 16) & 1u);
    return (short)(r >> 16);
}

// LDS-only barrier: waits LDS ops, leaves global NT stores (vmcnt) in flight.
__device__ __forceinline__ void barrier_lgkm() {
    asm volatile("s_waitcnt lgkmcnt(0)" ::: "memory");
    __builtin_amdgcn_s_barrier();
    __builtin_amdgcn_sched_barrier(0);
}

// ---------------- prep: pack bf16 fragments + row norms ----------------
// chunk(g,kk,lg,lr) = bf16 of M[g*16+lr][kk*32+lg*8 .. +8]
// => main-kernel frag load: 64 lanes read ((g*4+kk)*64+lane)*16B, contiguous.
__global__ __launch_bounds__(256)
void prep_kernel(const float* __restrict__ X, const float* __restrict__ Y,
                 unsigned short* __restrict__ Xp, unsigned short* __restrict__ Yp,
                 float* __restrict__ xn, float* __restrict__ yn)
{
    const int t   = blockIdx.x * 256 + threadIdx.x;   // 0 .. 262143
    const int sel = t >> 17;                          // 0 = x, 1 = y
    const int c   = t & 131071;
    const int row = c >> 4;
    const int sub = c & 15;

    const float* src = (sel ? Y : X) + (size_t)row * DIM + sub * 8;
    f32x4 v0 = ((const f32x4*)src)[0];
    f32x4 v1 = ((const f32x4*)src)[1];

    short8 p;
    p[0]=f2bf(v0[0]); p[1]=f2bf(v0[1]); p[2]=f2bf(v0[2]); p[3]=f2bf(v0[3]);
    p[4]=f2bf(v1[0]); p[5]=f2bf(v1[1]); p[6]=f2bf(v1[2]); p[7]=f2bf(v1[3]);

    float part = v0[0]*v0[0] + v0[1]*v0[1] + v0[2]*v0[2] + v0[3]*v0[3]
               + v1[0]*v1[0] + v1[1]*v1[1] + v1[2]*v1[2] + v1[3]*v1[3];
    part += __shfl_xor(part, 1, 16);
    part += __shfl_xor(part, 2, 16);
    part += __shfl_xor(part, 4, 16);
    part += __shfl_xor(part, 8, 16);

    const int g = row >> 4, lr = row & 15, kk = sub >> 2, lg = sub & 3;
    unsigned short* dst = (sel ? Yp : Xp) + (size_t)(((g*4 + kk)*64) + lg*16 + lr) * 8;
    *(short8*)dst = p;
    if (sub == 0) (sel ? yn : xn)[row] = part;
}

// ---------------- main: 32x512 tile, 4 waves x (32 x 128) strips ----------------
__global__ __launch_bounds__(256, 3)
void dist_main(const unsigned short* __restrict__ Xp,
               const unsigned short* __restrict__ Yp,
               const float* __restrict__ xn, const float* __restrict__ yn,
               float* __restrict__ out)
{
    // 32 KiB: 16 rows x 2 KiB; 16B slots XOR-swizzled by (row&7).
    __shared__ char lds[16 * 2048];

    const int bid = blockIdx.x;
    const int wg  = (bid & 7) * 512 + (bid >> 3);   // XCD-bijective swizzle
    const int R0  = (wg >> 4) * 32;                 // 256 row bands
    const int C0  = (wg & 15) * 512;                // 16 col tiles

    const int t    = threadIdx.x;
    const int w    = t >> 6, lane = t & 63;
    const int lr   = lane & 15, lg = lane >> 4;

    const short8* Ap = (const short8*)Xp;
    const short8* Bp = (const short8*)Yp;
    const int ga = R0 >> 4;                         // 2 row groups: ga, ga+1
    const int gb = (C0 >> 4) + w * 8;               // 8 col groups per wave

    f32x4 acc[2][8];
    #pragma unroll
    for (int j = 0; j < 2; ++j)
        #pragma unroll
        for (int i = 0; i < 8; ++i)
            acc[j][i] = (f32x4){0.f, 0.f, 0.f, 0.f};

    #pragma unroll
    for (int kk = 0; kk < 4; ++kk) {
        short8 a0 = Ap[(size_t)(ga * 4 + kk) * 64 + lane];
        short8 a1 = Ap[(size_t)((ga + 1) * 4 + kk) * 64 + lane];
        // two b-halves of 4 to cap live VGPRs (R4 spill lesson)
        #pragma unroll
        for (int half = 0; half < 2; ++half) {
            short8 b[4];
            #pragma unroll
            for (int i = 0; i < 4; ++i)
                b[i] = Bp[(size_t)((gb + half * 4 + i) * 4 + kk) * 64 + lane];
            // D = mfma(B, A): D-row = y-index (out col), D-col = x-index (out row)
            #pragma unroll
            for (int i = 0; i < 4; ++i) {
                acc[0][half * 4 + i] = __builtin_amdgcn_mfma_f32_16x16x32_bf16(b[i], a0, acc[0][half * 4 + i], 0, 0, 0);
                acc[1][half * 4 + i] = __builtin_amdgcn_mfma_f32_16x16x32_bf16(b[i], a1, acc[1][half * 4 + i], 0, 0, 0);
            }
        }
    }

    // acc[j][i][r]:  n = R0 + j*16 + lr                (out row)
    //                m = C0 + w*128 + i*16 + lg*4 + r  (out col, f32x4-contig)
    float xnv[2];
    xnv[0] = xn[R0 + lr];
    xnv[1] = xn[R0 + 16 + lr];
    f32x4 ynv[8];
    #pragma unroll
    for (int i = 0; i < 8; ++i)
        ynv[i] = *(const f32x4*)(yn + C0 + w * 128 + i * 16 + lg * 4);

    // Two-pass epilogue (16 rows each): deposit fused values into swizzled
    // LDS, then each wave streams 4 rows as 2x 1KiB-contiguous NT stores
    // per row = 2 KiB sequential per row.
    #pragma unroll
    for (int p = 0; p < 2; ++p) {
        #pragma unroll
        for (int i = 0; i < 8; ++i) {
            f32x4 o;
            #pragma unroll
            for (int r = 0; r < 4; ++r)
                o[r] = xnv[p] + ynv[i][r] - 2.0f * acc[p][i][r];
            const int slotb = w * 512 + i * 64 + lg * 16;
            *(f32x4*)(lds + lr * 2048 + (slotb ^ ((lr & 7) << 4))) = o;
        }
        barrier_lgkm();
        #pragma unroll
        for (int rr = 0; rr < 4; ++rr) {
            const int lrow = w * 4 + rr;
            const size_t gbase = (size_t)(R0 + p * 16 + lrow) * NROW + C0;
            #pragma unroll
            for (int h = 0; h < 2; ++h) {
                const int s16 = h * 64 + lane;       // logical 16B chunk in row
                f32x4 v = *(const f32x4*)(lds + lrow * 2048 + ((s16 * 16) ^ ((lrow & 7) << 4)));
                __builtin_nontemporal_store(v, (f32x4*)(out + gbase + s16 * 4));
            }
        }
        if (p == 0) barrier_lgkm();
    }
}

// ---------------- fallback if ws_size too small ----------------
__global__ __launch_bounds__(256, 2)
void dist_fallback(const float* __restrict__ X, const float* __restrict__ Y,
                   float* __restrict__ out)
{
    __shared__ unsigned short As[128 * DIM];
    __shared__ unsigned short Bs[128 * DIM];
    __shared__ float xs[128];
    __shared__ float ys[128];

    const int t = threadIdx.x, bid = blockIdx.x;
    const int R0 = (bid >> 6) * 128, C0 = (bid & 63) * 128;
    {
        const float* gx = X + (size_t)R0 * DIM;
        const float* gy = Y + (size_t)C0 * DIM;
        char* lx = (char*)As; char* ly = (char*)Bs;
        #pragma unroll
        for (int i = 0; i < 8; ++i) {
            int q = i * 256 + t, r = q >> 4, c = q & 15;
            f32x4 a0 = ((const f32x4*)(gx + q*8))[0], a1 = ((const f32x4*)(gx + q*8))[1];
            f32x4 b0 = ((const f32x4*)(gy + q*8))[0], b1 = ((const f32x4*)(gy + q*8))[1];
            short8 pa, pb;
            #pragma unroll
            for (int e = 0; e < 4; ++e) { pa[e]=f2bf(a0[e]); pa[e+4]=f2bf(a1[e]); pb[e]=f2bf(b0[e]); pb[e+4]=f2bf(b1[e]); }
            int off = r * 256 + ((c * 16) ^ ((r & 7) << 4));
            *(short8*)(lx + off) = pa; *(short8*)(ly + off) = pb;
        }
    }
    {
        const float* row = (t < 128) ? (X + (size_t)(R0 + t) * DIM) : (Y + (size_t)(C0 + t - 128) * DIM);
        float s = 0.f;
        #pragma unroll
        for (int i = 0; i < DIM; i += 4) { f32x4 v = *(const f32x4*)(row + i); s += v[0]*v[0]+v[1]*v[1]+v[2]*v[2]+v[3]*v[3]; }
        if (t < 128) xs[t] = s; else ys[t - 128] = s;
    }
    __syncthreads();
    const int wid = t >> 6, lane = t & 63, wr = wid >> 1, wc = wid & 1, lg = lane >> 4, lrr = lane & 15;
    f32x4 acc[4][4];
    #pragma unroll
    for (int i = 0; i < 4; ++i) for (int j = 0; j < 4; ++j) acc[i][j] = (f32x4){0,0,0,0};
    const char* lA = (const char*)As; const char* lB = (const char*)Bs;
    #pragma unroll
    for (int kk = 0; kk < 4; ++kk) {
        const int kb = kk * 64 + lg * 16;
        short8 a[4], b[4];
        #pragma unroll
        for (int i = 0; i < 4; ++i) {
            int ar = wr*64 + i*16 + lrr; a[i] = *(const short8*)(lA + ar*256 + (kb ^ ((ar&7)<<4)));
            int br = wc*64 + i*16 + lrr; b[i] = *(const short8*)(lB + br*256 + (kb ^ ((br&7)<<4)));
        }
        #pragma unroll
        for (int i = 0; i < 4; ++i) for (int j = 0; j < 4; ++j)
            acc[i][j] = __builtin_amdgcn_mfma_f32_16x16x32_bf16(a[i], b[j], acc[i][j], 0, 0, 0);
    }
    #pragma unroll
    for (int i = 0; i < 4; ++i) for (int j = 0; j < 4; ++j) {
        const int row_l = wr*64 + i*16 + lg*4, col_l = wc*64 + j*16 + lrr;
        const float yv = ys[col_l];
        float* po = out + (size_t)(R0 + row_l) * NROW + (C0 + col_l);
        #pragma unroll
        for (int r = 0; r < 4; ++r) po[(size_t)r * NROW] = xs[row_l + r] + yv - 2.0f * acc[i][j][r];
    }
}

extern "C" void kernel_launch(void* const* d_in, const int* in_sizes, int n_in,
                              void* d_out, int out_size, void* d_ws, size_t ws_size,
                              hipStream_t stream) {
    const float* x = (const float*)d_in[0];
    const float* y = (const float*)d_in[1];
    float* out = (float*)d_out;

    const size_t XP_OFF = 0;
    const size_t YP_OFF = 2097152;            // 8192*128*2
    const size_t XN_OFF = 4194304;
    const size_t YN_OFF = 4194304 + 32768;
    const size_t NEED   = 4194304 + 65536;

    if (ws_size >= NEED) {
        char* w = (char*)d_ws;
        unsigned short* Xp = (unsigned short*)(w + XP_OFF);
        unsigned short* Yp = (unsigned short*)(w + YP_OFF);
        float* xnp = (float*)(w + XN_OFF);
        float* ynp = (float*)(w + YN_OFF);
        prep_kernel<<<1024, 256, 0, stream>>>(x, y, Xp, Yp, xnp, ynp);
        dist_main<<<4096, 256, 0, stream>>>(Xp, Yp, xnp, ynp, out);
    } else {
        dist_fallback<<<4096, 256, 0, stream>>>(x, y, out);
    }
}